// Round 17
// baseline (634.369 us; speedup 1.0000x reference)
//
#include <hip/hip_runtime.h>
#include <math.h>

// DeepSeekV3 MLA forward, MI355X gfx950.
// I/O fp32; internal math bf16 MFMA.
// Flash v10: v9 joint balanced-pair + SINGLE K buffer. r8 measured dbuf==no-dbuf
//            (78.4 vs 79.4: pipeline absorbed by TLP), so the 24.5KB second K
//            buffer is dead weight: dropping it -> 49KB LDS -> 3 blocks/CU
//            (+50% TLP against the measured 50% idle cycles). Split counted
//            waits kept: vmcnt(4) before QK^T (K done, V flying), vmcnt(0)
//            before PV.
// GEMMs r12 (measured 413->409): gemm8 256x128, tri-buffer, stage-ahead-2, vmcnt(3).
// Glue r8 (measured): transpose_all, norm_split, fused launches.
// B=2 S=2048 D=2048 H=16 NOPE=128 ROPE=64 DV=128 DQK=192 QLR=1536 KVLR=512

typedef unsigned short u16;
typedef __attribute__((ext_vector_type(8))) __bf16 bf16x8;
typedef __attribute__((ext_vector_type(4))) float f32x4;

#define DEV static __device__ __forceinline__

#if __has_builtin(__builtin_amdgcn_exp2f)
#define EXP2(x) __builtin_amdgcn_exp2f(x)
#else
#define EXP2(x) exp2f(x)
#endif

DEV float b2f(u16 v) { return __uint_as_float(((unsigned int)v) << 16); }
DEV u16 f2b(float f) {
  unsigned int u = __float_as_uint(f);
  u += 0x7fffu + ((u >> 16) & 1u);   // round-to-nearest-even
  return (u16)(u >> 16);
}
// native RTNE cvt -- compiler-generated, 1 instr, hazard-safe
DEV u16 f2b_hw(float f) {
  __bf16 h = (__bf16)f;
  u16 r;
  __builtin_memcpy(&r, &h, 2);
  return r;
}

DEV float waveReduceSum(float v) {
  #pragma unroll
  for (int o = 32; o > 0; o >>= 1) v += __shfl_down(v, o, 64);
  return v;
}

// async global->LDS, 16B per lane; LDS dest = wave-uniform base + lane*16
DEV void gld16(const u16* g, u16* l) {
  __builtin_amdgcn_global_load_lds((const __attribute__((address_space(1))) void*)g,
                                   (__attribute__((address_space(3))) void*)l, 16, 0, 0);
}

// ---------------- convert fp32 -> bf16 (flat) ----------------
__global__ __launch_bounds__(256)
void cvt_f32_bf16(const float* __restrict__ in, u16* __restrict__ out, int n4) {
  int i = blockIdx.x * 256 + threadIdx.x;
  if (i < n4) {
    float4 v = reinterpret_cast<const float4*>(in)[i];
    ushort4 o;
    o.x = f2b(v.x); o.y = f2b(v.y); o.z = f2b(v.z); o.w = f2b(v.w);
    reinterpret_cast<ushort4*>(out)[i] = o;
  }
}

// ---------------- fused transpose+convert of all 5 weights ----------------
__global__ __launch_bounds__(256)
void transpose_all(const float* __restrict__ Wqd, const float* __restrict__ Wkvd,
                   const float* __restrict__ Wqu, const float* __restrict__ Wkvu,
                   const float* __restrict__ Wo,
                   u16* __restrict__ W13T, u16* __restrict__ WquT,
                   u16* __restrict__ WkvuT, u16* __restrict__ WoT) {
  __shared__ u16 tile[32][33];
  int n = blockIdx.x;
  const float* in; u16* out; int R, C, gx, local;
  if (n < 3072)       { in = Wqd;  out = W13T;                        R = 2048; C = 1536; gx = 48;  local = n; }
  else if (n < 4224)  { in = Wkvd; out = W13T + (size_t)1536 * 2048;  R = 2048; C = 576;  gx = 18;  local = n - 3072; }
  else if (n < 8832)  { in = Wqu;  out = WquT;                        R = 1536; C = 3072; gx = 96;  local = n - 4224; }
  else if (n < 10880) { in = Wkvu; out = WkvuT;                       R = 512;  C = 4096; gx = 128; local = n - 8832; }
  else                { in = Wo;   out = WoT;                         R = 2048; C = 2048; gx = 64;  local = n - 10880; }
  int c0 = (local % gx) * 32, r0 = (local / gx) * 32;
  for (int i = threadIdx.y; i < 32; i += 8)
    tile[i][threadIdx.x] = f2b(in[(size_t)(r0 + i) * C + c0 + threadIdx.x]);
  __syncthreads();
  for (int i = threadIdx.y; i < 32; i += 8)
    out[(size_t)(c0 + i) * R + r0 + threadIdx.x] = tile[threadIdx.x][i];
}

// ---------------- gemm8 body: C[.][N] = A[.][K] * BT[N][K]^T (r12, measured) ----------------
template<int OUT_BF16>
DEV void gemm8_body(const u16* __restrict__ A, const u16* __restrict__ BT, void* __restrict__ Cp,
                    int N, int K, int gx, int nwg, int orig,
                    u16 (*As)[8192], u16 (*Bs)[4096]) {
  const int tid = threadIdx.x;           // 0..511
  const int lane = tid & 63;
  const int wave = tid >> 6;             // 0..7
  const int wm = (wave >> 1) * 64;       // 0/64/128/192
  const int wn = (wave & 1) * 64;        // 0/64
  const int q = lane >> 4;
  const int l16 = lane & 15;

  const int cpx = nwg >> 3;
  const int swz = (orig & 7) * cpx + (orig >> 3);
  const int bm = (swz / gx) * 256;
  const int bn = (swz % gx) * 128;

  auto stageA = [&](int buf, int k0) {
    #pragma unroll
    for (int i = 0; i < 2; i++) {
      int ub = i * 512 + wave * 64;
      int u = ub + lane;
      int row = u >> 2;
      int kq = (u & 3) ^ ((u >> 3) & 3);
      gld16(A + (size_t)(bm + row) * K + k0 + kq * 8, As[buf] + ub * 8);
    }
  };
  auto stageB = [&](int buf, int k0) {
    int ub = wave * 64;
    int u = ub + lane;
    int row = u >> 2;
    int kq = (u & 3) ^ ((u >> 3) & 3);
    int rB = bn + row;
    if (rB >= N) rB = N - 1;
    gld16(BT + (size_t)rB * K + k0 + kq * 8, Bs[buf] + ub * 8);
  };

  f32x4 zero = {0.f, 0.f, 0.f, 0.f};
  f32x4 acc[4][4];
  #pragma unroll
  for (int i = 0; i < 4; i++)
    #pragma unroll
    for (int j = 0; j < 4; j++) acc[i][j] = zero;

  const int nt = K >> 5;
  stageA(0, 0);  stageB(0, 0);
  stageA(1, 32); stageB(1, 32);

  for (int t = 0; t < nt; ++t) {
    const int cur = t % 3;
    if (t + 1 < nt) asm volatile("s_waitcnt vmcnt(3)" ::: "memory");
    else            asm volatile("s_waitcnt vmcnt(0)" ::: "memory");
    __builtin_amdgcn_sched_barrier(0);
    __builtin_amdgcn_s_barrier();
    __builtin_amdgcn_sched_barrier(0);

    const u16* Ab = As[cur];
    const u16* Bb = Bs[cur];
    const int nxt = (t + 2) % 3;
    const bool pre = (t + 2) < nt;
    const int kpre = (t + 2) * 32;

    bf16x8 af[4], bfr[4];
    #pragma unroll
    for (int j = 0; j < 4; j++) {
      int rowA = wm + j * 16 + l16;
      af[j]  = *reinterpret_cast<const bf16x8*>(Ab + (((rowA) << 2) | (q ^ ((rowA >> 1) & 3))) * 8);
      int rowB = wn + j * 16 + l16;
      bfr[j] = *reinterpret_cast<const bf16x8*>(Bb + (((rowB) << 2) | (q ^ ((rowB >> 1) & 3))) * 8);
    }
    if (pre) { stageA(nxt, kpre); stageB(nxt, kpre); }
    __builtin_amdgcn_s_setprio(1);
    #pragma unroll
    for (int mt = 0; mt < 4; mt++)
      #pragma unroll
      for (int j = 0; j < 4; j++)
        acc[mt][j] = __builtin_amdgcn_mfma_f32_16x16x32_bf16(af[mt], bfr[j], acc[mt][j], 0, 0, 0);
    __builtin_amdgcn_s_setprio(0);
  }

  float* Cf = (float*)Cp;
  u16* Cb = (u16*)Cp;
  #pragma unroll
  for (int mt = 0; mt < 4; mt++) {
    #pragma unroll
    for (int j = 0; j < 4; j++) {
      int col = bn + wn + j * 16 + l16;
      if (col < N) {
        int row0 = bm + wm + mt * 16 + q * 4;
        #pragma unroll
        for (int r = 0; r < 4; r++) {
          size_t idx = (size_t)(row0 + r) * N + col;
          float v = acc[mt][j][r];
          if (OUT_BF16) Cb[idx] = f2b(v); else Cf[idx] = v;
        }
      }
    }
  }
}

template<int OUT_BF16>
__global__ __launch_bounds__(512, 4)
void gemm8(const u16* __restrict__ A, const u16* __restrict__ BT, void* __restrict__ Cp,
           int N, int K) {
  __shared__ __attribute__((aligned(16))) u16 As[3][8192];
  __shared__ __attribute__((aligned(16))) u16 Bs[3][4096];
  const int gx = gridDim.x;
  const int nwg = gx * gridDim.y;
  const int orig = blockIdx.y * gx + blockIdx.x;
  gemm8_body<OUT_BF16>(A, BT, Cp, N, K, gx, nwg, orig, As, Bs);
}

// fused independent up-projections: blocks 0..383 = q-up, 384..895 = kv-up.
__global__ __launch_bounds__(512, 4)
void gemm_up2(const u16* __restrict__ qlat, const u16* __restrict__ WquT, u16* __restrict__ q2,
              const u16* __restrict__ kvl, const u16* __restrict__ WkvuT, u16* __restrict__ kvb) {
  __shared__ __attribute__((aligned(16))) u16 As[3][8192];
  __shared__ __attribute__((aligned(16))) u16 Bs[3][4096];
  int n = blockIdx.x;
  if (n < 384) gemm8_body<1>(qlat, WquT, q2, 3072, 1536, 24, 384, n, As, Bs);
  else         gemm8_body<1>(kvl, WkvuT, kvb, 4096, 512, 32, 512, n - 384, As, Bs);
}

// ---------------- fused norm/split ----------------
__global__ __launch_bounds__(256)
void norm_split(const float* __restrict__ t13, const float* __restrict__ fc, const float* __restrict__ fs,
                u16* __restrict__ qlat, u16* __restrict__ kvl, u16* __restrict__ krope) {
  __shared__ float red[4];
  __shared__ float s_scale;
  int lane = threadIdx.x & 63, wid = threadIdx.x >> 6;
  if (blockIdx.x < 4096) {
    int row = blockIdx.x;
    const float* x = t13 + (size_t)row * 2112;
    float ss = 0.f;
    for (int i = threadIdx.x; i < 1536; i += 256) { float v = x[i]; ss += v * v; }
    ss = waveReduceSum(ss);
    if (lane == 0) red[wid] = ss;
    __syncthreads();
    if (threadIdx.x == 0)
      s_scale = rsqrtf((red[0] + red[1] + red[2] + red[3]) * (1.0f / 1536.0f) + 1e-5f);
    __syncthreads();
    float sc = s_scale;
    u16* o = qlat + (size_t)row * 1536;
    for (int i = threadIdx.x; i < 1536; i += 256) o[i] = f2b(x[i] * sc);
  } else {
    int row = blockIdx.x - 4096;
    int s = row & 2047;
    const float* x = t13 + (size_t)row * 2112 + 1536;
    float ss = 0.f;
    for (int i = threadIdx.x; i < 512; i += 256) { float v = x[i]; ss += v * v; }
    ss = waveReduceSum(ss);
    if (lane == 0) red[wid] = ss;
    __syncthreads();
    if (threadIdx.x == 0)
      s_scale = rsqrtf((red[0] + red[1] + red[2] + red[3]) * (1.0f / 512.0f) + 1e-5f);
    __syncthreads();
    float sc = s_scale;
    for (int i = threadIdx.x; i < 512; i += 256) kvl[(size_t)row * 512 + i] = f2b(x[i] * sc);
    if (threadIdx.x < 32) {
      int i = threadIdx.x;
      float cc = fc[s * 32 + i], sn = fs[s * 32 + i];
      float x0 = x[512 + 2 * i], x1 = x[512 + 2 * i + 1];
      krope[(size_t)row * 64 + 2 * i]     = f2b(x0 * cc - x1 * sn);
      krope[(size_t)row * 64 + 2 * i + 1] = f2b(x0 * sn + x1 * cc);
    }
  }
}

// ---------------- rope + pack Q, PRESCALED by log2e/sqrt(192) ----------------
__global__ __launch_bounds__(256)
void rope_pack_q(const u16* __restrict__ q2, const float* __restrict__ fc, const float* __restrict__ fs,
                 u16* __restrict__ Q) {
  const float scale = 0.10411756711f;  // (1/sqrt(192)) * log2(e)
  int bs = blockIdx.x;
  int b = bs >> 11, s = bs & 2047;
  __shared__ float c[32], sn[32];
  if (threadIdx.x < 32) {
    c[threadIdx.x] = fc[s * 32 + threadIdx.x];
    sn[threadIdx.x] = fs[s * 32 + threadIdx.x];
  }
  __syncthreads();
  const u16* qrow = q2 + (size_t)bs * 3072;
  for (int t = threadIdx.x; t < 512; t += 256) {
    int h = t >> 5, i = t & 31;
    float x0 = b2f(qrow[h * 192 + 128 + 2 * i]);
    float x1 = b2f(qrow[h * 192 + 128 + 2 * i + 1]);
    size_t base = ((size_t)(b * 16 + h) * 2048 + s) * 192;
    Q[base + 2 * i]     = f2b((x0 * c[i] - x1 * sn[i]) * scale);
    Q[base + 2 * i + 1] = f2b((x0 * sn[i] + x1 * c[i]) * scale);
  }
  for (int t = threadIdx.x; t < 2048; t += 256) {
    int h = t >> 7, j = t & 127;
    Q[((size_t)(b * 16 + h) * 2048 + s) * 192 + 64 + j] = f2b(b2f(qrow[h * 192 + j]) * scale);
  }
}

// ---------------- assemble K chunked + V transposed chunked ----------------
__global__ __launch_bounds__(256)
void assemble_kv2(const u16* __restrict__ kvb, const u16* __restrict__ krope,
                  u16* __restrict__ Kc, u16* __restrict__ Vt) {
  int ks = blockIdx.x;   // 0..255
  int bh = blockIdx.y;   // 0..31
  int b = bh >> 4, h = bh & 15;
  int t = threadIdx.x;
  if (t < 192) {
    int kq = t >> 3, sl = t & 7;
    int s = ks * 8 + sl;
    size_t bs = (size_t)(b * 2048 + s);
    uint4 v;
    if (kq < 8) v = *reinterpret_cast<const uint4*>(krope + bs * 64 + kq * 8);
    else        v = *reinterpret_cast<const uint4*>(kvb + bs * 4096 + h * 128 + (kq - 8) * 8);
    *reinterpret_cast<uint4*>(Kc + (((size_t)bh * 24 + kq) * 2048 + s) * 8) = v;
  }
  if (t < 128) {
    int dv = t;
    u16 tmp[8];
    #pragma unroll
    for (int j = 0; j < 8; j++) {
      int s = ks * 8 + j;
      tmp[j] = kvb[(size_t)(b * 2048 + s) * 4096 + 2048 + h * 128 + dv];
    }
    *reinterpret_cast<uint4*>(Vt + (((size_t)bh * 256 + ks) * 128 + dv) * 8) = *reinterpret_cast<uint4*>(tmp);
  }
}

// ---------------- MFMA flash attention v10: joint pair, single K buf, 3 blocks/CU ----------------
__global__ __launch_bounds__(256, 3)
void flash_attn10(const u16* __restrict__ Q, const u16* __restrict__ Kc,
                  const u16* __restrict__ Vt, u16* __restrict__ O) {
  __shared__ __attribute__((aligned(16))) u16 Ks[24 * 64 * 8];   // 24 KB single buf
  __shared__ __attribute__((aligned(16))) u16 Vs[8 * 128 * 8];   // 16 KB
  __shared__ __attribute__((aligned(16))) u16 Ps[4 * 16 * 72];   // 9 KB per-wave

  const int blk = blockIdx.x;
  const int bh = ((blk & 7) << 2) | (blk >> 7);
  const int tpair = (blk >> 3) & 15;
  const int b = bh >> 4, h = bh & 15;
  const int tid = threadIdx.x, lane = tid & 63, wave = tid >> 6;
  const int quad = lane >> 4, l16 = lane & 15;
  u16* PsW = Ps + wave * 16 * 72;

  const int q0A = tpair * 64;          // small tile: keys < nkA
  const int q0B = (31 - tpair) * 64;   // big tile:  keys < nkB
  const int nkA = q0A + 64;
  const int nkB = q0B + 64;

  bf16x8 onesf;
  #pragma unroll
  for (int j = 0; j < 8; j++) onesf[j] = (l16 == 0) ? (__bf16)1.0f : (__bf16)0.0f;

  auto stageK = [&](int kk) {
    #pragma unroll
    for (int ii = 0; ii < 6; ii++) {
      int kq = wave * 6 + ii;
      gld16(Kc + (((size_t)bh * 24 + kq) * 2048 + kk + lane) * 8, Ks + kq * 64 * 8);
    }
  };
  auto stageV = [&](int kk) {
    #pragma unroll
    for (int jj = 0; jj < 4; jj++) {
      int vc = wave * 4 + jj, kc = vc >> 1, dvh = vc & 1;
      gld16(Vt + (((size_t)bh * 256 + (kk >> 3) + kc) * 128 + dvh * 64 + lane) * 8,
            Vs + (kc * 128 + dvh * 64) * 8);
    }
  };

  // Q fragments for both sub-tiles (sub 0 = A, sub 1 = B)
  bf16x8 qf[2][6];
  #pragma unroll
  for (int s = 0; s < 2; s++) {
    int qrow = (s ? q0B : q0A) + wave * 16 + l16;
    const u16* qp = Q + ((size_t)bh * 2048 + qrow) * 192 + quad * 8;
    #pragma unroll
    for (int kc = 0; kc < 6; kc++)
      qf[s][kc] = *reinterpret_cast<const bf16x8*>(qp + kc * 32);
  }

  f32x4 zero = {0.f, 0.f, 0.f, 0.f};
  f32x4 oacc[2][9];
  #pragma unroll
  for (int s = 0; s < 2; s++)
    #pragma unroll
    for (int nt = 0; nt < 9; nt++) oacc[s][nt] = zero;

  for (int k0 = 0; k0 < nkB; k0 += 64) {
    const bool aA = (k0 < nkA);          // block-uniform

    // BAR_a: all waves done with prev step's Ks (QK^T) and Vs (PV) reads
    __builtin_amdgcn_s_barrier();
    __builtin_amdgcn_sched_barrier(0);
    stageK(k0);                           // 6 loads
    stageV(k0);                           // 4 loads
    asm volatile("s_waitcnt vmcnt(4)" ::: "memory");   // K done; V flying
    __builtin_amdgcn_sched_barrier(0);
    __builtin_amdgcn_s_barrier();        // BAR_b: K visible to all waves
    __builtin_amdgcn_sched_barrier(0);

    // QK^T: K fragments reused across both sub-tiles when A active
    f32x4 sacc[2][4];
    #pragma unroll
    for (int s = 0; s < 2; s++)
      #pragma unroll
      for (int nt = 0; nt < 4; nt++) sacc[s][nt] = zero;
    if (aA) {
      #pragma unroll
      for (int kc = 0; kc < 6; kc++) {
        #pragma unroll
        for (int nt = 0; nt < 4; nt++) {
          bf16x8 kb = *reinterpret_cast<const bf16x8*>(Ks + ((kc * 4 + quad) * 64 + nt * 16 + l16) * 8);
          sacc[1][nt] = __builtin_amdgcn_mfma_f32_16x16x32_bf16(qf[1][kc], kb, sacc[1][nt], 0, 0, 0);
          sacc[0][nt] = __builtin_amdgcn_mfma_f32_16x16x32_bf16(qf[0][kc], kb, sacc[0][nt], 0, 0, 0);
        }
      }
    } else {
      #pragma unroll
      for (int kc = 0; kc < 6; kc++) {
        #pragma unroll
        for (int nt = 0; nt < 4; nt++) {
          bf16x8 kb = *reinterpret_cast<const bf16x8*>(Ks + ((kc * 4 + quad) * 64 + nt * 16 + l16) * 8);
          sacc[1][nt] = __builtin_amdgcn_mfma_f32_16x16x32_bf16(qf[1][kc], kb, sacc[1][nt], 0, 0, 0);
        }
      }
    }

    // softmax for sub-tile s into PsW (exp2 domain; wave-uniform mask hoist)
    auto softmax = [&](int s, int q0s) {
      if (k0 + 63 <= q0s + wave * 16) {
        #pragma unroll
        for (int r = 0; r < 4; r++)
          #pragma unroll
          for (int nt = 0; nt < 4; nt++) {
            float p = EXP2(sacc[s][nt][r]);
            PsW[(quad * 4 + r) * 72 + nt * 16 + l16] = f2b_hw(p);
          }
      } else {
        #pragma unroll
        for (int r = 0; r < 4; r++) {
          int qrow_g = q0s + wave * 16 + quad * 4 + r;
          #pragma unroll
          for (int nt = 0; nt < 4; nt++) {
            int key = k0 + nt * 16 + l16;
            float e = EXP2(sacc[s][nt][r]);
            float p = (key <= qrow_g) ? e : 0.f;
            PsW[(quad * 4 + r) * 72 + nt * 16 + l16] = f2b_hw(p);
          }
        }
      }
    };
    auto pv = [&](int s) {
      #pragma unroll
      for (int kcp = 0; kcp < 2; kcp++) {
        bf16x8 pa = *reinterpret_cast<const bf16x8*>(PsW + l16 * 72 + kcp * 32 + quad * 8);
        #pragma unroll
        for (int nt = 0; nt < 8; nt++) {
          bf16x8 vb = *reinterpret_cast<const bf16x8*>(Vs + ((kcp * 4 + quad) * 128 + nt * 16 + l16) * 8);
          oacc[s][nt] = __builtin_amdgcn_mfma_f32_16x16x32_bf16(pa, vb, oacc[s][nt], 0, 0, 0);
        }
        oacc[s][8] = __builtin_amdgcn_mfma_f32_16x16x32_bf16(pa, onesf, oacc[s][8], 0, 0, 0);
      }
    };

    softmax(1, q0B);
    asm volatile("s_waitcnt vmcnt(0)" ::: "memory");   // V done
    __builtin_amdgcn_sched_barrier(0);
    __builtin_amdgcn_s_barrier();        // BAR_c: V visible to all waves
    __builtin_amdgcn_sched_barrier(0);
    pv(1);
    if (aA) {                            // Ps reuse: wave-private, program-ordered
      softmax(0, q0A);
      pv(0);
    }
  }

  // epilogue: both sub-tiles; l at l16==0 of each quad, broadcast within quad
  #pragma unroll
  for (int s = 0; s < 2; s++) {
    int q0s = s ? q0B : q0A;
    #pragma unroll
    for (int r = 0; r < 4; r++) {
      float l = __shfl(oacc[s][8][r], lane & 48, 64);
      float inv = 1.0f / l;
      int sr = q0s + wave * 16 + quad * 4 + r;
      #pragma unroll
      for (int nt = 0; nt < 8; nt++)
        O[((size_t)b * 2048 + sr) * 2048 + h * 128 + nt * 16 + l16] = f2b(oacc[s][nt][r] * inv);
    }
  }
}

// ---------------- launch ----------------
extern "C" void kernel_launch(void* const* d_in, const int* in_sizes, int n_in,
                              void* d_out, int out_size, void* d_ws, size_t ws_size,
                              hipStream_t stream) {
  (void)in_sizes; (void)n_in; (void)out_size; (void)ws_size;
  const float* hs   = (const float*)d_in[0];
  const float* fc   = (const float*)d_in[2];
  const float* fs   = (const float*)d_in[3];
  const float* Wqd  = (const float*)d_in[4];
  const float* Wkvd = (const float*)d_in[5];
  const float* Wqu  = (const float*)d_in[6];
  const float* Wkvu = (const float*)d_in[7];
  const float* Wo   = (const float*)d_in[8];

  char* ws = (char*)d_ws;
  size_t off = 0;
  auto alloc = [&](size_t bytes) { size_t o = off; off += (bytes + 255) & ~(size_t)255; return o; };
  const size_t oHS   = alloc(16777216);  // hs_bf bf16 [4096][2048]
  const size_t oRA   = alloc(16777216);  // Vt bf16 [32][256][128][8]
  const size_t oRB   = alloc(25165824);  // q2 bf16 [4096][3072] -> Kc bf16
  const size_t oRC   = alloc(12582912);  // qlat bf16 [4096][1536]
  const size_t oRD   = alloc(25165824);  // Q bf16 [B*H][S][192]
  const size_t oRE   = alloc(34603008);  // t13 f32 [4096][2112] -> kvb bf16 -> attn_out
  const size_t oKVL  = alloc(4194304);   // kvl bf16 [4096][512]
  const size_t oKR   = alloc(524288);    // krope bf16 [4096][64]
  const size_t oW13T  = alloc(8650752);  // [2112][2048] bf16
  const size_t oWquT  = alloc(9437184);
  const size_t oWkvuT = alloc(4194304);
  const size_t oWoT   = alloc(8388608);

  u16* hs_bf = (u16*)(ws + oHS);
  u16* Vt   = (u16*)(ws + oRA);
  u16* q2   = (u16*)(ws + oRB);
  u16* Kc   = (u16*)(ws + oRB);
  u16* qlat = (u16*)(ws + oRC);
  u16* Qb   = (u16*)(ws + oRD);
  float* t13 = (float*)(ws + oRE);
  u16* kvb  = (u16*)(ws + oRE);
  u16* attn_out = (u16*)(ws + oRE);
  u16* kvl  = (u16*)(ws + oKVL);
  u16* krope = (u16*)(ws + oKR);
  u16* W13T  = (u16*)(ws + oW13T);
  u16* WquT  = (u16*)(ws + oWquT);
  u16* WkvuT = (u16*)(ws + oWkvuT);
  u16* WoT   = (u16*)(ws + oWoT);

  cvt_f32_bf16<<<8192, 256, 0, stream>>>(hs, hs_bf, 2097152);
  transpose_all<<<14976, dim3(32, 8), 0, stream>>>(Wqd, Wkvd, Wqu, Wkvu, Wo, W13T, WquT, WkvuT, WoT);

  // fused down-projections: t13 = hs @ [Wq_down | Wkv_down]
  gemm8<0><<<dim3(17, 16), 512, 0, stream>>>(hs_bf, W13T, t13, 2112, 2048);
  // fused rmsnorm(q-latent) + kv split
  norm_split<<<8192, 256, 0, stream>>>(t13, fc, fs, qlat, kvl, krope);
  // fused independent up-projections (concurrent): q2 and kvb
  gemm_up2<<<896, 512, 0, stream>>>(qlat, WquT, q2, kvl, WkvuT, kvb);
  // rope+pack Q (reads q2 BEFORE Kc overwrites the same buffer in assemble_kv2)
  rope_pack_q<<<4096, 256, 0, stream>>>(q2, fc, fs, Qb);
  assemble_kv2<<<dim3(256, 32), 256, 0, stream>>>(kvb, krope, Kc, Vt);
  // attention v10 (joint pair, single K buf, 3 blocks/CU)
  flash_attn10<<<dim3(512), 256, 0, stream>>>(Qb, Kc, Vt, attn_out);
  // output projection (fp32 out)
  gemm8<0><<<dim3(16, 16), 512, 0, stream>>>(attn_out, WoT, (float*)d_out, 2048, 2048);
}

// Round 20
// 429.398 us; speedup vs baseline: 1.4773x; 1.4773x over previous
//
#include <hip/hip_runtime.h>
#include <math.h>

// DeepSeekV3 MLA forward, MI355X gfx950.
// I/O fp32; internal math bf16 MFMA.
// Flash v10b: v10 (joint pair + single K buf, 49KB -> 3 blocks/CU by LDS) with
//             launch_bounds(256,2): r17 PMC showed (256,3) forced the allocator
//             to 84 VGPR -> accumulator spill to scratch (WRITE_SIZE 16MB->624MB,
//             ~300us). With (256,2) the allocator gets 256-VGPR headroom (v9
//             measured 128) and runtime occupancy = min(LDS 3, VGPR 4) = 3
//             blocks/CU -- the intended TLP without the spill.
// GEMMs r12 (measured 409): gemm8 256x128, tri-buffer, stage-ahead-2, vmcnt(3).
// Glue r8 (measured): transpose_all, norm_split, fused launches.
// B=2 S=2048 D=2048 H=16 NOPE=128 ROPE=64 DV=128 DQK=192 QLR=1536 KVLR=512

typedef unsigned short u16;
typedef __attribute__((ext_vector_type(8))) __bf16 bf16x8;
typedef __attribute__((ext_vector_type(4))) float f32x4;

#define DEV static __device__ __forceinline__

#if __has_builtin(__builtin_amdgcn_exp2f)
#define EXP2(x) __builtin_amdgcn_exp2f(x)
#else
#define EXP2(x) exp2f(x)
#endif

DEV float b2f(u16 v) { return __uint_as_float(((unsigned int)v) << 16); }
DEV u16 f2b(float f) {
  unsigned int u = __float_as_uint(f);
  u += 0x7fffu + ((u >> 16) & 1u);   // round-to-nearest-even
  return (u16)(u >> 16);
}
// native RTNE cvt -- compiler-generated, 1 instr, hazard-safe
DEV u16 f2b_hw(float f) {
  __bf16 h = (__bf16)f;
  u16 r;
  __builtin_memcpy(&r, &h, 2);
  return r;
}

DEV float waveReduceSum(float v) {
  #pragma unroll
  for (int o = 32; o > 0; o >>= 1) v += __shfl_down(v, o, 64);
  return v;
}

// async global->LDS, 16B per lane; LDS dest = wave-uniform base + lane*16
DEV void gld16(const u16* g, u16* l) {
  __builtin_amdgcn_global_load_lds((const __attribute__((address_space(1))) void*)g,
                                   (__attribute__((address_space(3))) void*)l, 16, 0, 0);
}

// ---------------- convert fp32 -> bf16 (flat) ----------------
__global__ __launch_bounds__(256)
void cvt_f32_bf16(const float* __restrict__ in, u16* __restrict__ out, int n4) {
  int i = blockIdx.x * 256 + threadIdx.x;
  if (i < n4) {
    float4 v = reinterpret_cast<const float4*>(in)[i];
    ushort4 o;
    o.x = f2b(v.x); o.y = f2b(v.y); o.z = f2b(v.z); o.w = f2b(v.w);
    reinterpret_cast<ushort4*>(out)[i] = o;
  }
}

// ---------------- fused transpose+convert of all 5 weights ----------------
__global__ __launch_bounds__(256)
void transpose_all(const float* __restrict__ Wqd, const float* __restrict__ Wkvd,
                   const float* __restrict__ Wqu, const float* __restrict__ Wkvu,
                   const float* __restrict__ Wo,
                   u16* __restrict__ W13T, u16* __restrict__ WquT,
                   u16* __restrict__ WkvuT, u16* __restrict__ WoT) {
  __shared__ u16 tile[32][33];
  int n = blockIdx.x;
  const float* in; u16* out; int R, C, gx, local;
  if (n < 3072)       { in = Wqd;  out = W13T;                        R = 2048; C = 1536; gx = 48;  local = n; }
  else if (n < 4224)  { in = Wkvd; out = W13T + (size_t)1536 * 2048;  R = 2048; C = 576;  gx = 18;  local = n - 3072; }
  else if (n < 8832)  { in = Wqu;  out = WquT;                        R = 1536; C = 3072; gx = 96;  local = n - 4224; }
  else if (n < 10880) { in = Wkvu; out = WkvuT;                       R = 512;  C = 4096; gx = 128; local = n - 8832; }
  else                { in = Wo;   out = WoT;                         R = 2048; C = 2048; gx = 64;  local = n - 10880; }
  int c0 = (local % gx) * 32, r0 = (local / gx) * 32;
  for (int i = threadIdx.y; i < 32; i += 8)
    tile[i][threadIdx.x] = f2b(in[(size_t)(r0 + i) * C + c0 + threadIdx.x]);
  __syncthreads();
  for (int i = threadIdx.y; i < 32; i += 8)
    out[(size_t)(c0 + i) * R + r0 + threadIdx.x] = tile[threadIdx.x][i];
}

// ---------------- gemm8 body: C[.][N] = A[.][K] * BT[N][K]^T (r12, measured) ----------------
template<int OUT_BF16>
DEV void gemm8_body(const u16* __restrict__ A, const u16* __restrict__ BT, void* __restrict__ Cp,
                    int N, int K, int gx, int nwg, int orig,
                    u16 (*As)[8192], u16 (*Bs)[4096]) {
  const int tid = threadIdx.x;           // 0..511
  const int lane = tid & 63;
  const int wave = tid >> 6;             // 0..7
  const int wm = (wave >> 1) * 64;       // 0/64/128/192
  const int wn = (wave & 1) * 64;        // 0/64
  const int q = lane >> 4;
  const int l16 = lane & 15;

  const int cpx = nwg >> 3;
  const int swz = (orig & 7) * cpx + (orig >> 3);
  const int bm = (swz / gx) * 256;
  const int bn = (swz % gx) * 128;

  auto stageA = [&](int buf, int k0) {
    #pragma unroll
    for (int i = 0; i < 2; i++) {
      int ub = i * 512 + wave * 64;
      int u = ub + lane;
      int row = u >> 2;
      int kq = (u & 3) ^ ((u >> 3) & 3);
      gld16(A + (size_t)(bm + row) * K + k0 + kq * 8, As[buf] + ub * 8);
    }
  };
  auto stageB = [&](int buf, int k0) {
    int ub = wave * 64;
    int u = ub + lane;
    int row = u >> 2;
    int kq = (u & 3) ^ ((u >> 3) & 3);
    int rB = bn + row;
    if (rB >= N) rB = N - 1;
    gld16(BT + (size_t)rB * K + k0 + kq * 8, Bs[buf] + ub * 8);
  };

  f32x4 zero = {0.f, 0.f, 0.f, 0.f};
  f32x4 acc[4][4];
  #pragma unroll
  for (int i = 0; i < 4; i++)
    #pragma unroll
    for (int j = 0; j < 4; j++) acc[i][j] = zero;

  const int nt = K >> 5;
  stageA(0, 0);  stageB(0, 0);
  stageA(1, 32); stageB(1, 32);

  for (int t = 0; t < nt; ++t) {
    const int cur = t % 3;
    if (t + 1 < nt) asm volatile("s_waitcnt vmcnt(3)" ::: "memory");
    else            asm volatile("s_waitcnt vmcnt(0)" ::: "memory");
    __builtin_amdgcn_sched_barrier(0);
    __builtin_amdgcn_s_barrier();
    __builtin_amdgcn_sched_barrier(0);

    const u16* Ab = As[cur];
    const u16* Bb = Bs[cur];
    const int nxt = (t + 2) % 3;
    const bool pre = (t + 2) < nt;
    const int kpre = (t + 2) * 32;

    bf16x8 af[4], bfr[4];
    #pragma unroll
    for (int j = 0; j < 4; j++) {
      int rowA = wm + j * 16 + l16;
      af[j]  = *reinterpret_cast<const bf16x8*>(Ab + (((rowA) << 2) | (q ^ ((rowA >> 1) & 3))) * 8);
      int rowB = wn + j * 16 + l16;
      bfr[j] = *reinterpret_cast<const bf16x8*>(Bb + (((rowB) << 2) | (q ^ ((rowB >> 1) & 3))) * 8);
    }
    if (pre) { stageA(nxt, kpre); stageB(nxt, kpre); }
    __builtin_amdgcn_s_setprio(1);
    #pragma unroll
    for (int mt = 0; mt < 4; mt++)
      #pragma unroll
      for (int j = 0; j < 4; j++)
        acc[mt][j] = __builtin_amdgcn_mfma_f32_16x16x32_bf16(af[mt], bfr[j], acc[mt][j], 0, 0, 0);
    __builtin_amdgcn_s_setprio(0);
  }

  float* Cf = (float*)Cp;
  u16* Cb = (u16*)Cp;
  #pragma unroll
  for (int mt = 0; mt < 4; mt++) {
    #pragma unroll
    for (int j = 0; j < 4; j++) {
      int col = bn + wn + j * 16 + l16;
      if (col < N) {
        int row0 = bm + wm + mt * 16 + q * 4;
        #pragma unroll
        for (int r = 0; r < 4; r++) {
          size_t idx = (size_t)(row0 + r) * N + col;
          float v = acc[mt][j][r];
          if (OUT_BF16) Cb[idx] = f2b(v); else Cf[idx] = v;
        }
      }
    }
  }
}

template<int OUT_BF16>
__global__ __launch_bounds__(512, 4)
void gemm8(const u16* __restrict__ A, const u16* __restrict__ BT, void* __restrict__ Cp,
           int N, int K) {
  __shared__ __attribute__((aligned(16))) u16 As[3][8192];
  __shared__ __attribute__((aligned(16))) u16 Bs[3][4096];
  const int gx = gridDim.x;
  const int nwg = gx * gridDim.y;
  const int orig = blockIdx.y * gx + blockIdx.x;
  gemm8_body<OUT_BF16>(A, BT, Cp, N, K, gx, nwg, orig, As, Bs);
}

// fused independent up-projections: blocks 0..383 = q-up, 384..895 = kv-up.
__global__ __launch_bounds__(512, 4)
void gemm_up2(const u16* __restrict__ qlat, const u16* __restrict__ WquT, u16* __restrict__ q2,
              const u16* __restrict__ kvl, const u16* __restrict__ WkvuT, u16* __restrict__ kvb) {
  __shared__ __attribute__((aligned(16))) u16 As[3][8192];
  __shared__ __attribute__((aligned(16))) u16 Bs[3][4096];
  int n = blockIdx.x;
  if (n < 384) gemm8_body<1>(qlat, WquT, q2, 3072, 1536, 24, 384, n, As, Bs);
  else         gemm8_body<1>(kvl, WkvuT, kvb, 4096, 512, 32, 512, n - 384, As, Bs);
}

// ---------------- fused norm/split ----------------
__global__ __launch_bounds__(256)
void norm_split(const float* __restrict__ t13, const float* __restrict__ fc, const float* __restrict__ fs,
                u16* __restrict__ qlat, u16* __restrict__ kvl, u16* __restrict__ krope) {
  __shared__ float red[4];
  __shared__ float s_scale;
  int lane = threadIdx.x & 63, wid = threadIdx.x >> 6;
  if (blockIdx.x < 4096) {
    int row = blockIdx.x;
    const float* x = t13 + (size_t)row * 2112;
    float ss = 0.f;
    for (int i = threadIdx.x; i < 1536; i += 256) { float v = x[i]; ss += v * v; }
    ss = waveReduceSum(ss);
    if (lane == 0) red[wid] = ss;
    __syncthreads();
    if (threadIdx.x == 0)
      s_scale = rsqrtf((red[0] + red[1] + red[2] + red[3]) * (1.0f / 1536.0f) + 1e-5f);
    __syncthreads();
    float sc = s_scale;
    u16* o = qlat + (size_t)row * 1536;
    for (int i = threadIdx.x; i < 1536; i += 256) o[i] = f2b(x[i] * sc);
  } else {
    int row = blockIdx.x - 4096;
    int s = row & 2047;
    const float* x = t13 + (size_t)row * 2112 + 1536;
    float ss = 0.f;
    for (int i = threadIdx.x; i < 512; i += 256) { float v = x[i]; ss += v * v; }
    ss = waveReduceSum(ss);
    if (lane == 0) red[wid] = ss;
    __syncthreads();
    if (threadIdx.x == 0)
      s_scale = rsqrtf((red[0] + red[1] + red[2] + red[3]) * (1.0f / 512.0f) + 1e-5f);
    __syncthreads();
    float sc = s_scale;
    for (int i = threadIdx.x; i < 512; i += 256) kvl[(size_t)row * 512 + i] = f2b(x[i] * sc);
    if (threadIdx.x < 32) {
      int i = threadIdx.x;
      float cc = fc[s * 32 + i], sn = fs[s * 32 + i];
      float x0 = x[512 + 2 * i], x1 = x[512 + 2 * i + 1];
      krope[(size_t)row * 64 + 2 * i]     = f2b(x0 * cc - x1 * sn);
      krope[(size_t)row * 64 + 2 * i + 1] = f2b(x0 * sn + x1 * cc);
    }
  }
}

// ---------------- rope + pack Q, PRESCALED by log2e/sqrt(192) ----------------
__global__ __launch_bounds__(256)
void rope_pack_q(const u16* __restrict__ q2, const float* __restrict__ fc, const float* __restrict__ fs,
                 u16* __restrict__ Q) {
  const float scale = 0.10411756711f;  // (1/sqrt(192)) * log2(e)
  int bs = blockIdx.x;
  int b = bs >> 11, s = bs & 2047;
  __shared__ float c[32], sn[32];
  if (threadIdx.x < 32) {
    c[threadIdx.x] = fc[s * 32 + threadIdx.x];
    sn[threadIdx.x] = fs[s * 32 + threadIdx.x];
  }
  __syncthreads();
  const u16* qrow = q2 + (size_t)bs * 3072;
  for (int t = threadIdx.x; t < 512; t += 256) {
    int h = t >> 5, i = t & 31;
    float x0 = b2f(qrow[h * 192 + 128 + 2 * i]);
    float x1 = b2f(qrow[h * 192 + 128 + 2 * i + 1]);
    size_t base = ((size_t)(b * 16 + h) * 2048 + s) * 192;
    Q[base + 2 * i]     = f2b((x0 * c[i] - x1 * sn[i]) * scale);
    Q[base + 2 * i + 1] = f2b((x0 * sn[i] + x1 * c[i]) * scale);
  }
  for (int t = threadIdx.x; t < 2048; t += 256) {
    int h = t >> 7, j = t & 127;
    Q[((size_t)(b * 16 + h) * 2048 + s) * 192 + 64 + j] = f2b(b2f(qrow[h * 192 + j]) * scale);
  }
}

// ---------------- assemble K chunked + V transposed chunked ----------------
__global__ __launch_bounds__(256)
void assemble_kv2(const u16* __restrict__ kvb, const u16* __restrict__ krope,
                  u16* __restrict__ Kc, u16* __restrict__ Vt) {
  int ks = blockIdx.x;   // 0..255
  int bh = blockIdx.y;   // 0..31
  int b = bh >> 4, h = bh & 15;
  int t = threadIdx.x;
  if (t < 192) {
    int kq = t >> 3, sl = t & 7;
    int s = ks * 8 + sl;
    size_t bs = (size_t)(b * 2048 + s);
    uint4 v;
    if (kq < 8) v = *reinterpret_cast<const uint4*>(krope + bs * 64 + kq * 8);
    else        v = *reinterpret_cast<const uint4*>(kvb + bs * 4096 + h * 128 + (kq - 8) * 8);
    *reinterpret_cast<uint4*>(Kc + (((size_t)bh * 24 + kq) * 2048 + s) * 8) = v;
  }
  if (t < 128) {
    int dv = t;
    u16 tmp[8];
    #pragma unroll
    for (int j = 0; j < 8; j++) {
      int s = ks * 8 + j;
      tmp[j] = kvb[(size_t)(b * 2048 + s) * 4096 + 2048 + h * 128 + dv];
    }
    *reinterpret_cast<uint4*>(Vt + (((size_t)bh * 256 + ks) * 128 + dv) * 8) = *reinterpret_cast<uint4*>(tmp);
  }
}

// ---------------- MFMA flash attention v10b: joint pair, single K buf ----------------
// launch_bounds(256,2): allocator headroom (no spill); LDS 49KB gives 3 blocks/CU
// at runtime (min(LDS 3, VGPR 4)).
__global__ __launch_bounds__(256, 2)
void flash_attn10(const u16* __restrict__ Q, const u16* __restrict__ Kc,
                  const u16* __restrict__ Vt, u16* __restrict__ O) {
  __shared__ __attribute__((aligned(16))) u16 Ks[24 * 64 * 8];   // 24 KB single buf
  __shared__ __attribute__((aligned(16))) u16 Vs[8 * 128 * 8];   // 16 KB
  __shared__ __attribute__((aligned(16))) u16 Ps[4 * 16 * 72];   // 9 KB per-wave

  const int blk = blockIdx.x;
  const int bh = ((blk & 7) << 2) | (blk >> 7);
  const int tpair = (blk >> 3) & 15;
  const int b = bh >> 4, h = bh & 15;
  const int tid = threadIdx.x, lane = tid & 63, wave = tid >> 6;
  const int quad = lane >> 4, l16 = lane & 15;
  u16* PsW = Ps + wave * 16 * 72;

  const int q0A = tpair * 64;          // small tile: keys < nkA
  const int q0B = (31 - tpair) * 64;   // big tile:  keys < nkB
  const int nkA = q0A + 64;
  const int nkB = q0B + 64;

  bf16x8 onesf;
  #pragma unroll
  for (int j = 0; j < 8; j++) onesf[j] = (l16 == 0) ? (__bf16)1.0f : (__bf16)0.0f;

  auto stageK = [&](int kk) {
    #pragma unroll
    for (int ii = 0; ii < 6; ii++) {
      int kq = wave * 6 + ii;
      gld16(Kc + (((size_t)bh * 24 + kq) * 2048 + kk + lane) * 8, Ks + kq * 64 * 8);
    }
  };
  auto stageV = [&](int kk) {
    #pragma unroll
    for (int jj = 0; jj < 4; jj++) {
      int vc = wave * 4 + jj, kc = vc >> 1, dvh = vc & 1;
      gld16(Vt + (((size_t)bh * 256 + (kk >> 3) + kc) * 128 + dvh * 64 + lane) * 8,
            Vs + (kc * 128 + dvh * 64) * 8);
    }
  };

  // Q fragments for both sub-tiles (sub 0 = A, sub 1 = B)
  bf16x8 qf[2][6];
  #pragma unroll
  for (int s = 0; s < 2; s++) {
    int qrow = (s ? q0B : q0A) + wave * 16 + l16;
    const u16* qp = Q + ((size_t)bh * 2048 + qrow) * 192 + quad * 8;
    #pragma unroll
    for (int kc = 0; kc < 6; kc++)
      qf[s][kc] = *reinterpret_cast<const bf16x8*>(qp + kc * 32);
  }

  f32x4 zero = {0.f, 0.f, 0.f, 0.f};
  f32x4 oacc[2][9];
  #pragma unroll
  for (int s = 0; s < 2; s++)
    #pragma unroll
    for (int nt = 0; nt < 9; nt++) oacc[s][nt] = zero;

  for (int k0 = 0; k0 < nkB; k0 += 64) {
    const bool aA = (k0 < nkA);          // block-uniform

    // BAR_a: all waves done with prev step's Ks (QK^T) and Vs (PV) reads
    __builtin_amdgcn_s_barrier();
    __builtin_amdgcn_sched_barrier(0);
    stageK(k0);                           // 6 loads
    stageV(k0);                           // 4 loads
    asm volatile("s_waitcnt vmcnt(4)" ::: "memory");   // K done; V flying
    __builtin_amdgcn_sched_barrier(0);
    __builtin_amdgcn_s_barrier();        // BAR_b: K visible to all waves
    __builtin_amdgcn_sched_barrier(0);

    // QK^T: K fragments reused across both sub-tiles when A active
    f32x4 sacc[2][4];
    #pragma unroll
    for (int s = 0; s < 2; s++)
      #pragma unroll
      for (int nt = 0; nt < 4; nt++) sacc[s][nt] = zero;
    if (aA) {
      #pragma unroll
      for (int kc = 0; kc < 6; kc++) {
        #pragma unroll
        for (int nt = 0; nt < 4; nt++) {
          bf16x8 kb = *reinterpret_cast<const bf16x8*>(Ks + ((kc * 4 + quad) * 64 + nt * 16 + l16) * 8);
          sacc[1][nt] = __builtin_amdgcn_mfma_f32_16x16x32_bf16(qf[1][kc], kb, sacc[1][nt], 0, 0, 0);
          sacc[0][nt] = __builtin_amdgcn_mfma_f32_16x16x32_bf16(qf[0][kc], kb, sacc[0][nt], 0, 0, 0);
        }
      }
    } else {
      #pragma unroll
      for (int kc = 0; kc < 6; kc++) {
        #pragma unroll
        for (int nt = 0; nt < 4; nt++) {
          bf16x8 kb = *reinterpret_cast<const bf16x8*>(Ks + ((kc * 4 + quad) * 64 + nt * 16 + l16) * 8);
          sacc[1][nt] = __builtin_amdgcn_mfma_f32_16x16x32_bf16(qf[1][kc], kb, sacc[1][nt], 0, 0, 0);
        }
      }
    }

    // softmax for sub-tile s into PsW (exp2 domain; wave-uniform mask hoist)
    auto softmax = [&](int s, int q0s) {
      if (k0 + 63 <= q0s + wave * 16) {
        #pragma unroll
        for (int r = 0; r < 4; r++)
          #pragma unroll
          for (int nt = 0; nt < 4; nt++) {
            float p = EXP2(sacc[s][nt][r]);
            PsW[(quad * 4 + r) * 72 + nt * 16 + l16] = f2b_hw(p);
          }
      } else {
        #pragma unroll
        for (int r = 0; r < 4; r++) {
          int qrow_g = q0s + wave * 16 + quad * 4 + r;
          #pragma unroll
          for (int nt = 0; nt < 4; nt++) {
            int key = k0 + nt * 16 + l16;
            float e = EXP2(sacc[s][nt][r]);
            float p = (key <= qrow_g) ? e : 0.f;
            PsW[(quad * 4 + r) * 72 + nt * 16 + l16] = f2b_hw(p);
          }
        }
      }
    };
    auto pv = [&](int s) {
      #pragma unroll
      for (int kcp = 0; kcp < 2; kcp++) {
        bf16x8 pa = *reinterpret_cast<const bf16x8*>(PsW + l16 * 72 + kcp * 32 + quad * 8);
        #pragma unroll
        for (int nt = 0; nt < 8; nt++) {
          bf16x8 vb = *reinterpret_cast<const bf16x8*>(Vs + ((kcp * 4 + quad) * 128 + nt * 16 + l16) * 8);
          oacc[s][nt] = __builtin_amdgcn_mfma_f32_16x16x32_bf16(pa, vb, oacc[s][nt], 0, 0, 0);
        }
        oacc[s][8] = __builtin_amdgcn_mfma_f32_16x16x32_bf16(pa, onesf, oacc[s][8], 0, 0, 0);
      }
    };

    softmax(1, q0B);
    asm volatile("s_waitcnt vmcnt(0)" ::: "memory");   // V done
    __builtin_amdgcn_sched_barrier(0);
    __builtin_amdgcn_s_barrier();        // BAR_c: V visible to all waves
    __builtin_amdgcn_sched_barrier(0);
    pv(1);
    if (aA) {                            // Ps reuse: wave-private, program-ordered
      softmax(0, q0A);
      pv(0);
    }
  }

  // epilogue: both sub-tiles; l at l16==0 of each quad, broadcast within quad
  #pragma unroll
  for (int s = 0; s < 2; s++) {
    int q0s = s ? q0B : q0A;
    #pragma unroll
    for (int r = 0; r < 4; r++) {
      float l = __shfl(oacc[s][8][r], lane & 48, 64);
      float inv = 1.0f / l;
      int sr = q0s + wave * 16 + quad * 4 + r;
      #pragma unroll
      for (int nt = 0; nt < 8; nt++)
        O[((size_t)b * 2048 + sr) * 2048 + h * 128 + nt * 16 + l16] = f2b(oacc[s][nt][r] * inv);
    }
  }
}

// ---------------- launch ----------------
extern "C" void kernel_launch(void* const* d_in, const int* in_sizes, int n_in,
                              void* d_out, int out_size, void* d_ws, size_t ws_size,
                              hipStream_t stream) {
  (void)in_sizes; (void)n_in; (void)out_size; (void)ws_size;
  const float* hs   = (const float*)d_in[0];
  const float* fc   = (const float*)d_in[2];
  const float* fs   = (const float*)d_in[3];
  const float* Wqd  = (const float*)d_in[4];
  const float* Wkvd = (const float*)d_in[5];
  const float* Wqu  = (const float*)d_in[6];
  const float* Wkvu = (const float*)d_in[7];
  const float* Wo   = (const float*)d_in[8];

  char* ws = (char*)d_ws;
  size_t off = 0;
  auto alloc = [&](size_t bytes) { size_t o = off; off += (bytes + 255) & ~(size_t)255; return o; };
  const size_t oHS   = alloc(16777216);  // hs_bf bf16 [4096][2048]
  const size_t oRA   = alloc(16777216);  // Vt bf16 [32][256][128][8]
  const size_t oRB   = alloc(25165824);  // q2 bf16 [4096][3072] -> Kc bf16
  const size_t oRC   = alloc(12582912);  // qlat bf16 [4096][1536]
  const size_t oRD   = alloc(25165824);  // Q bf16 [B*H][S][192]
  const size_t oRE   = alloc(34603008);  // t13 f32 [4096][2112] -> kvb bf16 -> attn_out
  const size_t oKVL  = alloc(4194304);   // kvl bf16 [4096][512]
  const size_t oKR   = alloc(524288);    // krope bf16 [4096][64]
  const size_t oW13T  = alloc(8650752);  // [2112][2048] bf16
  const size_t oWquT  = alloc(9437184);
  const size_t oWkvuT = alloc(4194304);
  const size_t oWoT   = alloc(8388608);

  u16* hs_bf = (u16*)(ws + oHS);
  u16* Vt   = (u16*)(ws + oRA);
  u16* q2   = (u16*)(ws + oRB);
  u16* Kc   = (u16*)(ws + oRB);
  u16* qlat = (u16*)(ws + oRC);
  u16* Qb   = (u16*)(ws + oRD);
  float* t13 = (float*)(ws + oRE);
  u16* kvb  = (u16*)(ws + oRE);
  u16* attn_out = (u16*)(ws + oRE);
  u16* kvl  = (u16*)(ws + oKVL);
  u16* krope = (u16*)(ws + oKR);
  u16* W13T  = (u16*)(ws + oW13T);
  u16* WquT  = (u16*)(ws + oWquT);
  u16* WkvuT = (u16*)(ws + oWkvuT);
  u16* WoT   = (u16*)(ws + oWoT);

  cvt_f32_bf16<<<8192, 256, 0, stream>>>(hs, hs_bf, 2097152);
  transpose_all<<<14976, dim3(32, 8), 0, stream>>>(Wqd, Wkvd, Wqu, Wkvu, Wo, W13T, WquT, WkvuT, WoT);

  // fused down-projections: t13 = hs @ [Wq_down | Wkv_down]
  gemm8<0><<<dim3(17, 16), 512, 0, stream>>>(hs_bf, W13T, t13, 2112, 2048);
  // fused rmsnorm(q-latent) + kv split
  norm_split<<<8192, 256, 0, stream>>>(t13, fc, fs, qlat, kvl, krope);
  // fused independent up-projections (concurrent): q2 and kvb
  gemm_up2<<<896, 512, 0, stream>>>(qlat, WquT, q2, kvl, WkvuT, kvb);
  // rope+pack Q (reads q2 BEFORE Kc overwrites the same buffer in assemble_kv2)
  rope_pack_q<<<4096, 256, 0, stream>>>(q2, fc, fs, Qb);
  assemble_kv2<<<dim3(256, 32), 256, 0, stream>>>(kvb, krope, Kc, Vt);
  // attention v10b (joint pair, single K buf, no VGPR cap -> no spill)
  flash_attn10<<<dim3(512), 256, 0, stream>>>(Qb, Kc, Vt, attn_out);
  // output projection (fp32 out)
  gemm8<0><<<dim3(16, 16), 512, 0, stream>>>(attn_out, WoT, (float*)d_out, 2048, 2048);
}